// Round 13
// baseline (257.678 us; speedup 1.0000x reference)
//
#include <hip/hip_runtime.h>

#define P_ 3136
#define NTOT 50176
#define EPSV 1e-5f

typedef __bf16 bf16x8 __attribute__((ext_vector_type(8)));
typedef float f32x4 __attribute__((ext_vector_type(4)));
typedef unsigned short u16x8 __attribute__((ext_vector_type(8)));
typedef unsigned short u16x4 __attribute__((ext_vector_type(4)));

__device__ __forceinline__ unsigned short f2bf(float f) {
    unsigned u = __builtin_bit_cast(unsigned, f);
    unsigned r = u + 0x7fffu + ((u >> 16) & 1u);
    return (unsigned short)(r >> 16);
}
__device__ __forceinline__ float bf2f(unsigned short h) {
    unsigned u = ((unsigned)h) << 16;
    return __builtin_bit_cast(float, u);
}
// ---- OCP e4m3fn encode (RNE) / decode, consistent with gfx950 fp8 MFMA ----
__device__ __forceinline__ unsigned f2e4m3(float f) {
    unsigned u = __builtin_bit_cast(unsigned, f);
    unsigned s = (u >> 24) & 0x80u;
    float a = fabsf(f);
    if (a >= 448.f) return s | 0x7Eu;
    if (a < 0.015625f) {                       // subnormal: m = round(a * 2^9)
        int m = (int)(a * 512.f + 0.5f);       // m==8 -> 0x08 == 2^-6 (correct)
        return s | (unsigned)m;
    }
    unsigned au = __builtin_bit_cast(unsigned, a);
    unsigned r = au + 0x7FFFFu + ((au >> 20) & 1u);  // RNE at 3 mantissa bits
    unsigned e = (r >> 23) - 120u;                    // -127 + 7
    return s | (e << 3) | ((r >> 20) & 7u);
}
__device__ __forceinline__ float e4m3f(unsigned b) {
    unsigned em = b & 0x7fu;
    float v;
    if (em < 8u) v = (float)em * 0.001953125f;        // subnormal: m * 2^-9
    else v = __builtin_bit_cast(float, (((em >> 3) + 120u) << 23) | ((em & 7u) << 20));
    return (b & 0x80u) ? -v : v;
}
// tanh-approx GELU (max abs err ~1e-3; clamp avoids exp overflow NaN)
__device__ __forceinline__ float gelu_fast(float x) {
    float x2 = x * x;
    float u2 = x * (1.5957691216f + 0.0713548162f * x2);
    u2 = fminf(u2, 80.0f);
    float e = __expf(u2);
    return x * e * __builtin_amdgcn_rcpf(e + 1.0f);
}
__device__ __forceinline__ void gload16(const void* g, void* l) {
    __builtin_amdgcn_global_load_lds(
        (const __attribute__((address_space(1))) void*)g,
        (__attribute__((address_space(3))) void*)l, 16, 0, 0);
}
__device__ __forceinline__ bf16x8 ldlds(const char* p) {
    return __builtin_bit_cast(bf16x8, *(const u16x8*)p);
}

// ---------------- prep: weights -> bf16 (fc1, fc2) / fp8 x32 (gc), + BN fold ----------------
__global__ __launch_bounds__(256)
void prep_wb(const float* __restrict__ w1, const float* __restrict__ w2,
             const float* __restrict__ w3,
             unsigned short* __restrict__ o1, unsigned char* __restrict__ o2q,
             unsigned short* __restrict__ o3,
             const float* b1, const float* g1, const float* be1, const float* m1, const float* v1,
             const float* b2, const float* g2, const float* be2, const float* m2, const float* v2,
             const float* b3, const float* g3, const float* be3, const float* m3, const float* v3,
             float* bn1, float* bn2, float* bn3)
{
    int i = blockIdx.x * 256 + threadIdx.x;
    const int n1 = 384 * 384 / 4, n2 = 768 * 768 / 4, n3 = 384 * 768 / 4;
    if (i < n1) {
        float4 f = *(const float4*)(w1 + (size_t)i * 4);
        u16x4 pk = { f2bf(f.x), f2bf(f.y), f2bf(f.z), f2bf(f.w) };
        *(u16x4*)(o1 + (size_t)i * 4) = pk;
    } else if (i < n1 + n2) {
        int j = i - n1;
        float4 f = *(const float4*)(w2 + (size_t)j * 4);
        // gc weights scaled x32 into fp8 normal range; 1/32 folded into bn2.inv
        unsigned pk = f2e4m3(f.x * 32.f) | (f2e4m3(f.y * 32.f) << 8)
                    | (f2e4m3(f.z * 32.f) << 16) | (f2e4m3(f.w * 32.f) << 24);
        *(unsigned*)(o2q + (size_t)j * 4) = pk;
    } else if (i < n1 + n2 + n3) {
        int j = i - n1 - n2;
        float4 f = *(const float4*)(w3 + (size_t)j * 4);
        u16x4 pk = { f2bf(f.x), f2bf(f.y), f2bf(f.z), f2bf(f.w) };
        *(u16x4*)(o3 + (size_t)j * 4) = pk;
    } else {
        int k = i - (n1 + n2 + n3);  // 0..1535
        const float *pb, *pg, *pbe, *pm, *pv; float* dst; int o, M; float isc = 1.f;
        if (k < 384)       { pb=b1; pg=g1; pbe=be1; pm=m1; pv=v1; dst=bn1; o=k;      M=384; }
        else if (k < 1152) { pb=b2; pg=g2; pbe=be2; pm=m2; pv=v2; dst=bn2; o=k-384;  M=768; isc = 1.f/32.f; }
        else               { pb=b3; pg=g3; pbe=be3; pm=m3; pv=v3; dst=bn3; o=k-1152; M=384; }
        float inv = pg[o] / sqrtf(pv[o] + EPSV);
        dst[o]     = inv * isc;
        dst[M + o] = (pb[o] - pm[o]) * inv + pbe[o];
    }
}

// ---------------- prep: x [b][c][p] fp32 -> xT [bp][c] bf16 ----------------
__global__ __launch_bounds__(256)
void prep_xT(const float* __restrict__ x, unsigned short* __restrict__ xT)
{
    __shared__ float tl[64][65];
    const int t = threadIdx.x;
    const int c0 = blockIdx.x * 64;
    const int p0 = blockIdx.y * 64;
    const int b  = blockIdx.z;
    const float* xb = x + ((size_t)b * 384 + c0) * P_ + p0;
    {
        int c = t >> 2, j0 = (t & 3) * 16;
        #pragma unroll
        for (int j = 0; j < 16; j += 4) {
            float4 f4 = *(const float4*)(xb + (size_t)c * P_ + j0 + j);
            tl[c][j0 + j]     = f4.x; tl[c][j0 + j + 1] = f4.y;
            tl[c][j0 + j + 2] = f4.z; tl[c][j0 + j + 3] = f4.w;
        }
    }
    __syncthreads();
    {
        int p = t >> 2, c1 = (t & 3) * 16;
        unsigned short buf[16];
        #pragma unroll
        for (int j = 0; j < 16; ++j) buf[j] = f2bf(tl[c1 + j][p]);
        unsigned short* dst = xT + ((size_t)b * P_ + p0 + p) * 384 + c0 + c1;
        *(u16x8*)dst       = *(u16x8*)buf;
        *(u16x8*)(dst + 8) = *(u16x8*)(buf + 8);
    }
}

// ============ bf16 GEMM body (gemm1/gemm3): 128x128x64, 256 thr, r12 structure ============
// EPI 0: BN -> fp8 y [col][768B]+o0.  EPI 2: BN+res -> fp32 [b][o][p].
template<int KD, int MDIM, int EPI>
__device__ __forceinline__ void gemm_body(
    const unsigned short* __restrict__ W,
    const unsigned short* __restrict__ In,
    void* __restrict__ OutV,
    const float* __restrict__ bnp,
    const float* __restrict__ res,
    char* lds)
{
    constexpr int NT = KD / 64;
    constexpr int MT = MDIM / 128;

    const int t    = threadIdx.x;
    const int lane = t & 63;
    const int wave = t >> 6;
    const int wm = wave >> 1, wn = wave & 1;
    const int fr = lane & 15, fg = lane >> 4;

    const int nwg = gridDim.x;
    int id = blockIdx.x;
    int q = nwg >> 3, r = nwg & 7;
    int xcd = id & 7, pos = id >> 3;
    int wg = (xcd < r ? xcd * (q + 1) : r * (q + 1) + (xcd - r) * q) + pos;
    const int m0 = (wg % MT) * 128;
    const int n0 = (wg / MT) * 128;

    const int pcu  = (((t & 7) ^ ((t >> 3) & 7)) << 3);
    const int srow = t >> 3;
    const unsigned short* pA[4];
    const unsigned short* pB[4];
    #pragma unroll
    for (int i = 0; i < 4; ++i) {
        pA[i] = W  + (size_t)(m0 + i * 32 + srow) * KD + pcu;
        pB[i] = In + (size_t)(n0 + i * 32 + srow) * KD + pcu;
    }
    auto stage = [&](int kt) {
        int kk = kt * 64;
        char* base = lds + (kt & 1) * 32768 + t * 16;
        #pragma unroll
        for (int i = 0; i < 4; ++i) gload16(pA[i] + kk, base + i * 4096);
        #pragma unroll
        for (int i = 0; i < 4; ++i) gload16(pB[i] + kk, base + 16384 + i * 4096);
    };

    const int ko0 = (fg * 16) ^ ((fr & 7) << 4);
    const int ko1 = (64 + fg * 16) ^ ((fr & 7) << 4);
    const int arow = wm * 64 + fr;
    const int brow = wn * 64 + fr;

    f32x4 acc[4][4] = {};

    stage(0);

    for (int kt = 0; kt < NT; ++kt) {
        asm volatile("s_waitcnt vmcnt(0)" ::: "memory");
        __builtin_amdgcn_s_barrier();
        __builtin_amdgcn_sched_barrier(0);
        if (kt + 1 < NT) stage(kt + 1);
        __builtin_amdgcn_sched_barrier(0);

        const char* base = lds + (kt & 1) * 32768;
        bf16x8 afr[4][2], bfr[4][2];
        #pragma unroll
        for (int mf = 0; mf < 4; ++mf) {
            afr[mf][0] = ldlds(base + (arow + mf * 16) * 128 + ko0);
            afr[mf][1] = ldlds(base + (arow + mf * 16) * 128 + ko1);
        }
        #pragma unroll
        for (int nf = 0; nf < 4; ++nf) {
            bfr[nf][0] = ldlds(base + 16384 + (brow + nf * 16) * 128 + ko0);
            bfr[nf][1] = ldlds(base + 16384 + (brow + nf * 16) * 128 + ko1);
        }
        #pragma unroll
        for (int ks = 0; ks < 2; ++ks)
            #pragma unroll
            for (int mf = 0; mf < 4; ++mf)
                #pragma unroll
                for (int nf = 0; nf < 4; ++nf)
                    acc[mf][nf] = __builtin_amdgcn_mfma_f32_16x16x32_bf16(
                        afr[mf][ks], bfr[nf][ks], acc[mf][nf], 0, 0, 0);
    }

    asm volatile("s_waitcnt vmcnt(0)" ::: "memory");
    __builtin_amdgcn_s_barrier();

    if (EPI == 0) {
        // fp8 out: [128 col][144 byte] staging (144 = 16B-aligned rows)
        unsigned char* eL = (unsigned char*)lds;
        unsigned char* Out = (unsigned char*)OutV;
        #pragma unroll
        for (int mf = 0; mf < 4; ++mf) {
            const int o_l = wm * 64 + mf * 16 + fg * 4;
            f32x4 inv = *(const f32x4*)(bnp + m0 + o_l);
            f32x4 sh  = *(const f32x4*)(bnp + MDIM + m0 + o_l);
            #pragma unroll
            for (int nf = 0; nf < 4; ++nf) {
                const int col_l = wn * 64 + nf * 16 + fr;
                unsigned pk = 0;
                #pragma unroll
                for (int rr = 0; rr < 4; ++rr)
                    pk |= f2e4m3(acc[mf][nf][rr] * inv[rr] + sh[rr]) << (8 * rr);
                *(unsigned*)(eL + col_l * 144 + o_l) = pk;
            }
        }
        __builtin_amdgcn_s_barrier();
        #pragma unroll
        for (int it = 0; it < 8; ++it) {
            const int idx = it * 256 + t;
            const int col = idx >> 4, seg = idx & 15;
            *(unsigned long long*)(Out + (size_t)(n0 + col) * 768 + m0 + seg * 8) =
                *(const unsigned long long*)(eL + col * 144 + seg * 8);
        }
    } else {
        // fp32 + residual: single-phase [128 o][128 col] stage + pipelined IO
        float* eL = (float*)lds;
        float* Out = (float*)OutV;
        #pragma unroll
        for (int mf = 0; mf < 4; ++mf) {
            const int o_l = wm * 64 + mf * 16 + fg * 4;
            f32x4 inv = *(const f32x4*)(bnp + m0 + o_l);
            f32x4 sh  = *(const f32x4*)(bnp + MDIM + m0 + o_l);
            #pragma unroll
            for (int nf = 0; nf < 4; ++nf) {
                const int col_l = wn * 64 + nf * 16 + fr;
                #pragma unroll
                for (int rr = 0; rr < 4; ++rr)
                    eL[(o_l + rr) * 128 + col_l] = acc[mf][nf][rr] * inv[rr] + sh[rr];
            }
        }
        __builtin_amdgcn_s_barrier();
        const int b0 = n0 / P_;
        const int r0 = n0 - b0 * P_;
        #pragma unroll
        for (int g8 = 0; g8 < 8; ++g8) {
            size_t adr[8]; float ev[8], rv[8];
            #pragma unroll
            for (int u = 0; u < 8; ++u) {
                const int idx = (g8 * 8 + u) * 256 + t;
                const int o_i = idx >> 7, col = idx & 127;
                int p = r0 + col;
                const int wrap = p >= P_;
                p -= wrap ? P_ : 0;
                adr[u] = (size_t)(b0 + wrap) * 384 * P_ + (size_t)(m0 + o_i) * P_ + p;
                ev[u]  = eL[o_i * 128 + col];
                rv[u]  = res[adr[u]];
            }
            #pragma unroll
            for (int u = 0; u < 8; ++u)
                Out[adr[u]] = ev[u] + rv[u];
        }
    }
}

__global__ __launch_bounds__(256, 2)
void gemm1(const unsigned short* __restrict__ W, const unsigned short* __restrict__ In,
           void* __restrict__ OutV, const float* __restrict__ bnp)
{
    __shared__ __align__(16) char lds[65536];
    gemm_body<384, 384, 0>(W, In, OutV, bnp, nullptr, lds);
}
__global__ __launch_bounds__(256, 2)
void gemm3(const unsigned short* __restrict__ W, const unsigned short* __restrict__ In,
           void* __restrict__ OutV, const float* __restrict__ bnp,
           const float* __restrict__ res)
{
    __shared__ __align__(16) char lds[65536];
    gemm_body<768, 384, 2>(W, In, OutV, bnp, res, lds);
}

// ============ fp8 GEMM (gemm2): 128x128 tile, K-tile=128 fp8, 256 thr ============
// A = gc_w fp8 [768][768B] (x32-scaled), B = y fp8 [NTOT][768B].
// Same geometry as bf16 kernel: 128B rows, 16B-granule XOR(row&7) swizzle, b128 reads.
// One b128 = 16 fp8 = 2 MFMA inputs; same k-permutation applied to A and B keeps the
// dot product exact. NT=6 (half the barriers/staged bytes of the bf16 path).
__global__ __launch_bounds__(256, 2)
void gemm2q(const unsigned char* __restrict__ W,
            const unsigned char* __restrict__ In,
            unsigned short* __restrict__ Out,
            const float* __restrict__ bnp)
{
    constexpr int NT = 6;
    constexpr int MT = 6;
    __shared__ __align__(16) char lds[65536];

    const int t    = threadIdx.x;
    const int lane = t & 63;
    const int wave = t >> 6;
    const int wm = wave >> 1, wn = wave & 1;
    const int fr = lane & 15, fg = lane >> 4;

    const int nwg = gridDim.x;
    int id = blockIdx.x;
    int q = nwg >> 3, r = nwg & 7;
    int xcd = id & 7, pos = id >> 3;
    int wg = (xcd < r ? xcd * (q + 1) : r * (q + 1) + (xcd - r) * q) + pos;
    const int m0 = (wg % MT) * 128;
    const int n0 = (wg / MT) * 128;

    // staging: 16KB per operand per K-tile = 4 gloads each (rows 128B)
    const int pcu  = (((t & 7) ^ ((t >> 3) & 7)) << 4); // swizzled source byte offset
    const int srow = t >> 3;                             // 0..31
    const unsigned char* pA[4];
    const unsigned char* pB[4];
    #pragma unroll
    for (int i = 0; i < 4; ++i) {
        pA[i] = W  + (size_t)(m0 + i * 32 + srow) * 768 + pcu;
        pB[i] = In + (size_t)(n0 + i * 32 + srow) * 768 + pcu;
    }
    auto stage = [&](int kt) {
        int kk = kt * 128;
        char* base = lds + (kt & 1) * 32768 + t * 16;
        #pragma unroll
        for (int i = 0; i < 4; ++i) gload16(pA[i] + kk, base + i * 4096);
        #pragma unroll
        for (int i = 0; i < 4; ++i) gload16(pB[i] + kk, base + 16384 + i * 4096);
    };

    const int ko0 = (fg * 16) ^ ((fr & 7) << 4);
    const int ko1 = (64 + fg * 16) ^ ((fr & 7) << 4);
    const int arow = wm * 64 + fr;
    const int brow = wn * 64 + fr;

    f32x4 acc[4][4] = {};

    stage(0);

    for (int kt = 0; kt < NT; ++kt) {
        asm volatile("s_waitcnt vmcnt(0)" ::: "memory");
        __builtin_amdgcn_s_barrier();
        __builtin_amdgcn_sched_barrier(0);
        if (kt + 1 < NT) stage(kt + 1);
        __builtin_amdgcn_sched_barrier(0);

        const char* base = lds + (kt & 1) * 32768;
        ulonglong2 afr[4][2], bfr[4][2];
        #pragma unroll
        for (int mf = 0; mf < 4; ++mf) {
            afr[mf][0] = *(const ulonglong2*)(base + (arow + mf * 16) * 128 + ko0);
            afr[mf][1] = *(const ulonglong2*)(base + (arow + mf * 16) * 128 + ko1);
        }
        #pragma unroll
        for (int nf = 0; nf < 4; ++nf) {
            bfr[nf][0] = *(const ulonglong2*)(base + 16384 + (brow + nf * 16) * 128 + ko0);
            bfr[nf][1] = *(const ulonglong2*)(base + 16384 + (brow + nf * 16) * 128 + ko1);
        }
        #pragma unroll
        for (int rd = 0; rd < 2; ++rd)
            #pragma unroll
            for (int hf = 0; hf < 2; ++hf)
                #pragma unroll
                for (int mf = 0; mf < 4; ++mf)
                    #pragma unroll
                    for (int nf = 0; nf < 4; ++nf)
                        acc[mf][nf] = __builtin_amdgcn_mfma_f32_16x16x32_fp8_fp8(
                            (long)(hf ? afr[mf][rd].y : afr[mf][rd].x),
                            (long)(hf ? bfr[nf][rd].y : bfr[nf][rd].x),
                            acc[mf][nf], 0, 0, 0);
    }

    asm volatile("s_waitcnt vmcnt(0)" ::: "memory");
    __builtin_amdgcn_s_barrier();

    // BN + gelu -> bf16 g: [128 col][136 u16] staging
    unsigned short* eL = (unsigned short*)lds;
    #pragma unroll
    for (int mf = 0; mf < 4; ++mf) {
        const int o_l = wm * 64 + mf * 16 + fg * 4;
        f32x4 inv = *(const f32x4*)(bnp + m0 + o_l);
        f32x4 sh  = *(const f32x4*)(bnp + 768 + m0 + o_l);
        #pragma unroll
        for (int nf = 0; nf < 4; ++nf) {
            const int col_l = wn * 64 + nf * 16 + fr;
            u16x4 pk;
            #pragma unroll
            for (int rr = 0; rr < 4; ++rr)
                pk[rr] = f2bf(gelu_fast(acc[mf][nf][rr] * inv[rr] + sh[rr]));
            *(u16x4*)(eL + col_l * 136 + o_l) = pk;
        }
    }
    __builtin_amdgcn_s_barrier();
    #pragma unroll
    for (int i = 0; i < 8; ++i) {
        const int col_l = (t >> 4) + i * 16;
        const int o8 = (t & 15) * 8;
        u16x8 v = *(const u16x8*)(eL + col_l * 136 + o8);
        *(u16x8*)(Out + (size_t)(n0 + col_l) * 768 + m0 + o8) = v;
    }
}

// ---------------- mrconv pass 1 (fp8 y): per-(b, w|h) parity mins ----------------
#define MINSEG (16 * 2 * 56 * 384)
__global__ __launch_bounds__(384)
void mr_min(const unsigned char* __restrict__ y, float* __restrict__ mins)
{
    const int c = threadIdx.x;
    const int q = blockIdx.x;
    const int b = blockIdx.y;
    const unsigned char* yb = y + (size_t)b * P_ * 768;
    float m1e = 3.4e38f, m2e = 3.4e38f, m1o = 3.4e38f, m2o = 3.4e38f;
    if (q < 56) {
        int w = q;
        for (int h = 0; h < 56; h += 2) {
            float v0 = e4m3f(yb[(size_t)(h * 56 + w) * 768 + c]);
            float v1 = e4m3f(yb[(size_t)((h + 1) * 56 + w) * 768 + c]);
            if (v0 < m1e) { m2e = m1e; m1e = v0; } else if (v0 < m2e) m2e = v0;
            if (v1 < m1o) { m2o = m1o; m1o = v1; } else if (v1 < m2o) m2o = v1;
        }
        float* cm1 = mins;
        float* cm2 = mins + MINSEG;
        cm1[((b * 2 + 0) * 56 + w) * 384 + c] = m1e;
        cm1[((b * 2 + 1) * 56 + w) * 384 + c] = m1o;
        cm2[((b * 2 + 0) * 56 + w) * 384 + c] = m2e;
        cm2[((b * 2 + 1) * 56 + w) * 384 + c] = m2o;
    } else {
        int h = q - 56;
        for (int w = 0; w < 56; w += 2) {
            float v0 = e4m3f(yb[(size_t)(h * 56 + w) * 768 + c]);
            float v1 = e4m3f(yb[(size_t)(h * 56 + w + 1) * 768 + c]);
            if (v0 < m1e) { m2e = m1e; m1e = v0; } else if (v0 < m2e) m2e = v0;
            if (v1 < m1o) { m2o = m1o; m1o = v1; } else if (v1 < m2o) m2o = v1;
        }
        float* rm1 = mins + 2 * MINSEG;
        float* rm2 = mins + 3 * MINSEG;
        rm1[((b * 2 + 0) * 56 + h) * 384 + c] = m1e;
        rm1[((b * 2 + 1) * 56 + h) * 384 + c] = m1o;
        rm2[((b * 2 + 0) * 56 + h) * 384 + c] = m2e;
        rm2[((b * 2 + 1) * 56 + h) * 384 + c] = m2o;
    }
}

// ---------------- mrconv pass 2 (fp8 y): combine -> y[:, 384:768] ----------------
__global__ __launch_bounds__(384)
void mr_comb(unsigned char* __restrict__ y, const float* __restrict__ mins)
{
    const int c = threadIdx.x;
    const int h = blockIdx.x;
    const int b = blockIdx.y;
    unsigned char* yb = y + (size_t)b * P_ * 768;
    const float* cm1 = mins;
    const float* cm2 = mins + MINSEG;
    const float* rm1 = mins + 2 * MINSEG;
    const float* rm2 = mins + 3 * MINSEG;
    const int parh = h & 1;
    float r1e = rm1[((b * 2 + 0) * 56 + h) * 384 + c];
    float r2e = rm2[((b * 2 + 0) * 56 + h) * 384 + c];
    float r1o = rm1[((b * 2 + 1) * 56 + h) * 384 + c];
    float r2o = rm2[((b * 2 + 1) * 56 + h) * 384 + c];
    #pragma unroll 2
    for (int w = 0; w < 56; ++w) {
        float v  = e4m3f(yb[(size_t)(h * 56 + w) * 768 + c]);
        float c1 = cm1[((b * 2 + parh) * 56 + w) * 384 + c];
        float c2 = cm2[((b * 2 + parh) * 56 + w) * 384 + c];
        float mh = v > c1 ? c1 : c2;
        float rw1 = (w & 1) ? r1o : r1e;
        float rw2 = (w & 1) ? r2o : r2e;
        float mw = v > rw1 ? rw1 : rw2;
        float xj = fmaxf(0.0f, v - fminf(mh, mw));
        yb[(size_t)(h * 56 + w) * 768 + 384 + c] = (unsigned char)f2e4m3(xj);
    }
}

extern "C" void kernel_launch(void* const* d_in, const int* in_sizes, int n_in,
                              void* d_out, int out_size, void* d_ws, size_t ws_size,
                              hipStream_t stream)
{
    const float* x      = (const float*)d_in[0];
    const float* fc1_w  = (const float*)d_in[1];
    const float* fc1_b  = (const float*)d_in[2];
    const float* fc1_g  = (const float*)d_in[3];
    const float* fc1_be = (const float*)d_in[4];
    const float* fc1_m  = (const float*)d_in[5];
    const float* fc1_v  = (const float*)d_in[6];
    const float* gc_w   = (const float*)d_in[7];
    const float* gc_b   = (const float*)d_in[8];
    const float* gc_g   = (const float*)d_in[9];
    const float* gc_be  = (const float*)d_in[10];
    const float* gc_m   = (const float*)d_in[11];
    const float* gc_v   = (const float*)d_in[12];
    const float* fc2_w  = (const float*)d_in[13];
    const float* fc2_b  = (const float*)d_in[14];
    const float* fc2_g  = (const float*)d_in[15];
    const float* fc2_be = (const float*)d_in[16];
    const float* fc2_m  = (const float*)d_in[17];
    const float* fc2_v  = (const float*)d_in[18];

    char* ws = (char*)d_ws;
    unsigned char*  y   = (unsigned char*)ws;                        // [NTOT][768] fp8
    unsigned short* g   = (unsigned short*)(ws + (size_t)NTOT * 768);// [NTOT][768] bf16
    unsigned short* xT  = g + (size_t)NTOT * 768;                    // [NTOT][384] bf16
    unsigned short* wb1 = xT + (size_t)NTOT * 384;                   // [384][384] bf16
    unsigned short* wb3 = wb1 + 384 * 384;                           // [384][768] bf16
    unsigned char*  wb2q = (unsigned char*)(wb3 + 384 * 768);        // [768][768] fp8
    float* bn1 = (float*)(wb2q + 768 * 768);                         // [2][384]
    float* bn2 = bn1 + 2 * 384;                                      // [2][768]
    float* bn3 = bn2 + 2 * 768;                                      // [2][384]
    float* mins = bn3 + 2 * 384;                                     // 4 * MINSEG

    prep_wb<<<1014, 256, 0, stream>>>(fc1_w, gc_w, fc2_w, wb1, wb2q, wb3,
                                      fc1_b, fc1_g, fc1_be, fc1_m, fc1_v,
                                      gc_b, gc_g, gc_be, gc_m, gc_v,
                                      fc2_b, fc2_g, fc2_be, fc2_m, fc2_v,
                                      bn1, bn2, bn3);
    prep_xT<<<dim3(6, 49, 16), 256, 0, stream>>>(x, xT);

    // y[:, 0:384] = bn(fc1 @ x)  (fp8 out)
    gemm1<<<dim3(3 * 392), 256, 0, stream>>>(wb1, xT, y, bn1);
    // y[:, 384:768] = mrconv (two-pass, coalesced, fp8)
    mr_min<<<dim3(112, 16), 384, 0, stream>>>(y, mins);
    mr_comb<<<dim3(56, 16), 384, 0, stream>>>(y, mins);
    // g = gelu(bn(gc @ y))  (fp8 x fp8 -> bf16)
    gemm2q<<<dim3(6 * 392), 256, 0, stream>>>(wb2q, y, g, bn2);
    // out = bn(fc2 @ g) + x
    gemm3<<<dim3(3 * 392), 256, 0, stream>>>(wb3, g, (void*)d_out, bn3, x);
}

// Round 14
// 212.576 us; speedup vs baseline: 1.2122x; 1.2122x over previous
//
#include <hip/hip_runtime.h>

#define P_ 3136
#define NTOT 50176
#define EPSV 1e-5f

typedef __bf16 bf16x8 __attribute__((ext_vector_type(8)));
typedef float f32x4 __attribute__((ext_vector_type(4)));
typedef unsigned short u16x8 __attribute__((ext_vector_type(8)));
typedef unsigned short u16x4 __attribute__((ext_vector_type(4)));

__device__ __forceinline__ unsigned short f2bf(float f) {
    unsigned u = __builtin_bit_cast(unsigned, f);
    unsigned r = u + 0x7fffu + ((u >> 16) & 1u);
    return (unsigned short)(r >> 16);
}
__device__ __forceinline__ float bf2f(unsigned short h) {
    unsigned u = ((unsigned)h) << 16;
    return __builtin_bit_cast(float, u);
}

// ---- OCP e4m3fn encode/decode: hardware cvt when available, SW fallback ----
#if __has_builtin(__builtin_amdgcn_cvt_pk_fp8_f32) && __has_builtin(__builtin_amdgcn_cvt_f32_fp8)
#define FP8_HW 1
#else
#define FP8_HW 0
#endif

__device__ __forceinline__ unsigned f2e4m3_sw(float f) {
    unsigned u = __builtin_bit_cast(unsigned, f);
    unsigned s = (u >> 24) & 0x80u;
    float a = fabsf(f);
    if (a >= 448.f) return s | 0x7Eu;
    if (a < 0.015625f) {
        int m = (int)(a * 512.f + 0.5f);
        return s | (unsigned)m;
    }
    unsigned au = __builtin_bit_cast(unsigned, a);
    unsigned r = au + 0x7FFFFu + ((au >> 20) & 1u);
    unsigned e = (r >> 23) - 120u;
    return s | (e << 3) | ((r >> 20) & 7u);
}
__device__ __forceinline__ float e4m3f_sw(unsigned b) {
    unsigned em = b & 0x7fu;
    float v;
    if (em < 8u) v = (float)em * 0.001953125f;
    else v = __builtin_bit_cast(float, (((em >> 3) + 120u) << 23) | ((em & 7u) << 20));
    return (b & 0x80u) ? -v : v;
}
// pack 4 floats -> 4 fp8 bytes
__device__ __forceinline__ unsigned f2e4m3x4(float v0, float v1, float v2, float v3) {
#if FP8_HW
    unsigned pk = (unsigned)__builtin_amdgcn_cvt_pk_fp8_f32(v0, v1, 0, false);
    pk = (unsigned)__builtin_amdgcn_cvt_pk_fp8_f32(v2, v3, (int)pk, true);
    return pk;
#else
    return f2e4m3_sw(v0) | (f2e4m3_sw(v1) << 8) | (f2e4m3_sw(v2) << 16) | (f2e4m3_sw(v3) << 24);
#endif
}
__device__ __forceinline__ unsigned f2e4m3_1(float v) {
#if FP8_HW
    return (unsigned)__builtin_amdgcn_cvt_pk_fp8_f32(v, 0.f, 0, false) & 0xFFu;
#else
    return f2e4m3_sw(v);
#endif
}
__device__ __forceinline__ float e4m3f(unsigned b) {
#if FP8_HW
    return __builtin_amdgcn_cvt_f32_fp8((int)b, 0);
#else
    return e4m3f_sw(b);
#endif
}

// tanh-approx GELU (max abs err ~1e-3; clamp avoids exp overflow NaN)
__device__ __forceinline__ float gelu_fast(float x) {
    float x2 = x * x;
    float u2 = x * (1.5957691216f + 0.0713548162f * x2);
    u2 = fminf(u2, 80.0f);
    float e = __expf(u2);
    return x * e * __builtin_amdgcn_rcpf(e + 1.0f);
}
__device__ __forceinline__ void gload16(const void* g, void* l) {
    __builtin_amdgcn_global_load_lds(
        (const __attribute__((address_space(1))) void*)g,
        (__attribute__((address_space(3))) void*)l, 16, 0, 0);
}
__device__ __forceinline__ bf16x8 ldlds(const char* p) {
    return __builtin_bit_cast(bf16x8, *(const u16x8*)p);
}

// ---------------- prep: weights -> bf16 (fc1, fc2) / fp8 x32 (gc), + BN fold ----------------
__global__ __launch_bounds__(256)
void prep_wb(const float* __restrict__ w1, const float* __restrict__ w2,
             const float* __restrict__ w3,
             unsigned short* __restrict__ o1, unsigned char* __restrict__ o2q,
             unsigned short* __restrict__ o3,
             const float* b1, const float* g1, const float* be1, const float* m1, const float* v1,
             const float* b2, const float* g2, const float* be2, const float* m2, const float* v2,
             const float* b3, const float* g3, const float* be3, const float* m3, const float* v3,
             float* bn1, float* bn2, float* bn3)
{
    int i = blockIdx.x * 256 + threadIdx.x;
    const int n1 = 384 * 384 / 4, n2 = 768 * 768 / 4, n3 = 384 * 768 / 4;
    if (i < n1) {
        float4 f = *(const float4*)(w1 + (size_t)i * 4);
        u16x4 pk = { f2bf(f.x), f2bf(f.y), f2bf(f.z), f2bf(f.w) };
        *(u16x4*)(o1 + (size_t)i * 4) = pk;
    } else if (i < n1 + n2) {
        int j = i - n1;
        float4 f = *(const float4*)(w2 + (size_t)j * 4);
        // gc weights scaled x32 into fp8 normal range; 1/32 folded into bn2.inv
        *(unsigned*)(o2q + (size_t)j * 4) =
            f2e4m3x4(f.x * 32.f, f.y * 32.f, f.z * 32.f, f.w * 32.f);
    } else if (i < n1 + n2 + n3) {
        int j = i - n1 - n2;
        float4 f = *(const float4*)(w3 + (size_t)j * 4);
        u16x4 pk = { f2bf(f.x), f2bf(f.y), f2bf(f.z), f2bf(f.w) };
        *(u16x4*)(o3 + (size_t)j * 4) = pk;
    } else {
        int k = i - (n1 + n2 + n3);  // 0..1535
        const float *pb, *pg, *pbe, *pm, *pv; float* dst; int o, M; float isc = 1.f;
        if (k < 384)       { pb=b1; pg=g1; pbe=be1; pm=m1; pv=v1; dst=bn1; o=k;      M=384; }
        else if (k < 1152) { pb=b2; pg=g2; pbe=be2; pm=m2; pv=v2; dst=bn2; o=k-384;  M=768; isc = 1.f/32.f; }
        else               { pb=b3; pg=g3; pbe=be3; pm=m3; pv=v3; dst=bn3; o=k-1152; M=384; }
        float inv = pg[o] / sqrtf(pv[o] + EPSV);
        dst[o]     = inv * isc;
        dst[M + o] = (pb[o] - pm[o]) * inv + pbe[o];
    }
}

// ---------------- prep: x [b][c][p] fp32 -> xT [bp][c] bf16 ----------------
__global__ __launch_bounds__(256)
void prep_xT(const float* __restrict__ x, unsigned short* __restrict__ xT)
{
    __shared__ float tl[64][65];
    const int t = threadIdx.x;
    const int c0 = blockIdx.x * 64;
    const int p0 = blockIdx.y * 64;
    const int b  = blockIdx.z;
    const float* xb = x + ((size_t)b * 384 + c0) * P_ + p0;
    {
        int c = t >> 2, j0 = (t & 3) * 16;
        #pragma unroll
        for (int j = 0; j < 16; j += 4) {
            float4 f4 = *(const float4*)(xb + (size_t)c * P_ + j0 + j);
            tl[c][j0 + j]     = f4.x; tl[c][j0 + j + 1] = f4.y;
            tl[c][j0 + j + 2] = f4.z; tl[c][j0 + j + 3] = f4.w;
        }
    }
    __syncthreads();
    {
        int p = t >> 2, c1 = (t & 3) * 16;
        unsigned short buf[16];
        #pragma unroll
        for (int j = 0; j < 16; ++j) buf[j] = f2bf(tl[c1 + j][p]);
        unsigned short* dst = xT + ((size_t)b * P_ + p0 + p) * 384 + c0 + c1;
        *(u16x8*)dst       = *(u16x8*)buf;
        *(u16x8*)(dst + 8) = *(u16x8*)(buf + 8);
    }
}

// ============ bf16 GEMM body (gemm1/gemm3): 128x128x64, 256 thr ============
// EPI 0: BN -> fp8 y [col][768B]+o0.  EPI 2: BN+res -> fp32 [b][o][p].
template<int KD, int MDIM, int EPI>
__device__ __forceinline__ void gemm_body(
    const unsigned short* __restrict__ W,
    const unsigned short* __restrict__ In,
    void* __restrict__ OutV,
    const float* __restrict__ bnp,
    const float* __restrict__ res,
    char* lds)
{
    constexpr int NT = KD / 64;
    constexpr int MT = MDIM / 128;

    const int t    = threadIdx.x;
    const int lane = t & 63;
    const int wave = t >> 6;
    const int wm = wave >> 1, wn = wave & 1;
    const int fr = lane & 15, fg = lane >> 4;

    const int nwg = gridDim.x;
    int id = blockIdx.x;
    int q = nwg >> 3, r = nwg & 7;
    int xcd = id & 7, pos = id >> 3;
    int wg = (xcd < r ? xcd * (q + 1) : r * (q + 1) + (xcd - r) * q) + pos;
    const int m0 = (wg % MT) * 128;
    const int n0 = (wg / MT) * 128;

    const int pcu  = (((t & 7) ^ ((t >> 3) & 7)) << 3);
    const int srow = t >> 3;
    const unsigned short* pA[4];
    const unsigned short* pB[4];
    #pragma unroll
    for (int i = 0; i < 4; ++i) {
        pA[i] = W  + (size_t)(m0 + i * 32 + srow) * KD + pcu;
        pB[i] = In + (size_t)(n0 + i * 32 + srow) * KD + pcu;
    }
    auto stage = [&](int kt) {
        int kk = kt * 64;
        char* base = lds + (kt & 1) * 32768 + t * 16;
        #pragma unroll
        for (int i = 0; i < 4; ++i) gload16(pA[i] + kk, base + i * 4096);
        #pragma unroll
        for (int i = 0; i < 4; ++i) gload16(pB[i] + kk, base + 16384 + i * 4096);
    };

    const int ko0 = (fg * 16) ^ ((fr & 7) << 4);
    const int ko1 = (64 + fg * 16) ^ ((fr & 7) << 4);
    const int arow = wm * 64 + fr;
    const int brow = wn * 64 + fr;

    f32x4 acc[4][4] = {};

    stage(0);

    for (int kt = 0; kt < NT; ++kt) {
        asm volatile("s_waitcnt vmcnt(0)" ::: "memory");
        __builtin_amdgcn_s_barrier();
        __builtin_amdgcn_sched_barrier(0);
        if (kt + 1 < NT) stage(kt + 1);
        __builtin_amdgcn_sched_barrier(0);

        const char* base = lds + (kt & 1) * 32768;
        bf16x8 afr[4][2], bfr[4][2];
        #pragma unroll
        for (int mf = 0; mf < 4; ++mf) {
            afr[mf][0] = ldlds(base + (arow + mf * 16) * 128 + ko0);
            afr[mf][1] = ldlds(base + (arow + mf * 16) * 128 + ko1);
        }
        #pragma unroll
        for (int nf = 0; nf < 4; ++nf) {
            bfr[nf][0] = ldlds(base + 16384 + (brow + nf * 16) * 128 + ko0);
            bfr[nf][1] = ldlds(base + 16384 + (brow + nf * 16) * 128 + ko1);
        }
        #pragma unroll
        for (int ks = 0; ks < 2; ++ks)
            #pragma unroll
            for (int mf = 0; mf < 4; ++mf)
                #pragma unroll
                for (int nf = 0; nf < 4; ++nf)
                    acc[mf][nf] = __builtin_amdgcn_mfma_f32_16x16x32_bf16(
                        afr[mf][ks], bfr[nf][ks], acc[mf][nf], 0, 0, 0);
    }

    asm volatile("s_waitcnt vmcnt(0)" ::: "memory");
    __builtin_amdgcn_s_barrier();

    if (EPI == 0) {
        // fp8 out: [128 col][144 byte] staging (144 = 16B-aligned rows)
        unsigned char* eL = (unsigned char*)lds;
        unsigned char* Out = (unsigned char*)OutV;
        #pragma unroll
        for (int mf = 0; mf < 4; ++mf) {
            const int o_l = wm * 64 + mf * 16 + fg * 4;
            f32x4 inv = *(const f32x4*)(bnp + m0 + o_l);
            f32x4 sh  = *(const f32x4*)(bnp + MDIM + m0 + o_l);
            #pragma unroll
            for (int nf = 0; nf < 4; ++nf) {
                const int col_l = wn * 64 + nf * 16 + fr;
                *(unsigned*)(eL + col_l * 144 + o_l) = f2e4m3x4(
                    acc[mf][nf][0] * inv[0] + sh[0],
                    acc[mf][nf][1] * inv[1] + sh[1],
                    acc[mf][nf][2] * inv[2] + sh[2],
                    acc[mf][nf][3] * inv[3] + sh[3]);
            }
        }
        __builtin_amdgcn_s_barrier();
        #pragma unroll
        for (int it = 0; it < 8; ++it) {
            const int idx = it * 256 + t;
            const int col = idx >> 4, seg = idx & 15;
            *(unsigned long long*)(Out + (size_t)(n0 + col) * 768 + m0 + seg * 8) =
                *(const unsigned long long*)(eL + col * 144 + seg * 8);
        }
    } else {
        // fp32 + residual: single-phase [128 o][128 col] stage + pipelined IO
        float* eL = (float*)lds;
        float* Out = (float*)OutV;
        #pragma unroll
        for (int mf = 0; mf < 4; ++mf) {
            const int o_l = wm * 64 + mf * 16 + fg * 4;
            f32x4 inv = *(const f32x4*)(bnp + m0 + o_l);
            f32x4 sh  = *(const f32x4*)(bnp + MDIM + m0 + o_l);
            #pragma unroll
            for (int nf = 0; nf < 4; ++nf) {
                const int col_l = wn * 64 + nf * 16 + fr;
                #pragma unroll
                for (int rr = 0; rr < 4; ++rr)
                    eL[(o_l + rr) * 128 + col_l] = acc[mf][nf][rr] * inv[rr] + sh[rr];
            }
        }
        __builtin_amdgcn_s_barrier();
        const int b0 = n0 / P_;
        const int r0 = n0 - b0 * P_;
        #pragma unroll
        for (int g8 = 0; g8 < 8; ++g8) {
            size_t adr[8]; float ev[8], rv[8];
            #pragma unroll
            for (int u = 0; u < 8; ++u) {
                const int idx = (g8 * 8 + u) * 256 + t;
                const int o_i = idx >> 7, col = idx & 127;
                int p = r0 + col;
                const int wrap = p >= P_;
                p -= wrap ? P_ : 0;
                adr[u] = (size_t)(b0 + wrap) * 384 * P_ + (size_t)(m0 + o_i) * P_ + p;
                ev[u]  = eL[o_i * 128 + col];
                rv[u]  = res[adr[u]];
            }
            #pragma unroll
            for (int u = 0; u < 8; ++u)
                Out[adr[u]] = ev[u] + rv[u];
        }
    }
}

__global__ __launch_bounds__(256, 2)
void gemm1(const unsigned short* __restrict__ W, const unsigned short* __restrict__ In,
           void* __restrict__ OutV, const float* __restrict__ bnp)
{
    __shared__ __align__(16) char lds[65536];
    gemm_body<384, 384, 0>(W, In, OutV, bnp, nullptr, lds);
}
__global__ __launch_bounds__(256, 2)
void gemm3(const unsigned short* __restrict__ W, const unsigned short* __restrict__ In,
           void* __restrict__ OutV, const float* __restrict__ bnp,
           const float* __restrict__ res)
{
    __shared__ __align__(16) char lds[65536];
    gemm_body<768, 384, 2>(W, In, OutV, bnp, res, lds);
}

// ============ fp8 GEMM (gemm2): 128x128 tile, K-tile=128 fp8, 256 thr ============
__global__ __launch_bounds__(256, 2)
void gemm2q(const unsigned char* __restrict__ W,
            const unsigned char* __restrict__ In,
            unsigned short* __restrict__ Out,
            const float* __restrict__ bnp)
{
    constexpr int NT = 6;
    constexpr int MT = 6;
    __shared__ __align__(16) char lds[65536];

    const int t    = threadIdx.x;
    const int lane = t & 63;
    const int wave = t >> 6;
    const int wm = wave >> 1, wn = wave & 1;
    const int fr = lane & 15, fg = lane >> 4;

    const int nwg = gridDim.x;
    int id = blockIdx.x;
    int q = nwg >> 3, r = nwg & 7;
    int xcd = id & 7, pos = id >> 3;
    int wg = (xcd < r ? xcd * (q + 1) : r * (q + 1) + (xcd - r) * q) + pos;
    const int m0 = (wg % MT) * 128;
    const int n0 = (wg / MT) * 128;

    const int pcu  = (((t & 7) ^ ((t >> 3) & 7)) << 4);
    const int srow = t >> 3;
    const unsigned char* pA[4];
    const unsigned char* pB[4];
    #pragma unroll
    for (int i = 0; i < 4; ++i) {
        pA[i] = W  + (size_t)(m0 + i * 32 + srow) * 768 + pcu;
        pB[i] = In + (size_t)(n0 + i * 32 + srow) * 768 + pcu;
    }
    auto stage = [&](int kt) {
        int kk = kt * 128;
        char* base = lds + (kt & 1) * 32768 + t * 16;
        #pragma unroll
        for (int i = 0; i < 4; ++i) gload16(pA[i] + kk, base + i * 4096);
        #pragma unroll
        for (int i = 0; i < 4; ++i) gload16(pB[i] + kk, base + 16384 + i * 4096);
    };

    const int ko0 = (fg * 16) ^ ((fr & 7) << 4);
    const int ko1 = (64 + fg * 16) ^ ((fr & 7) << 4);
    const int arow = wm * 64 + fr;
    const int brow = wn * 64 + fr;

    f32x4 acc[4][4] = {};

    stage(0);

    for (int kt = 0; kt < NT; ++kt) {
        asm volatile("s_waitcnt vmcnt(0)" ::: "memory");
        __builtin_amdgcn_s_barrier();
        __builtin_amdgcn_sched_barrier(0);
        if (kt + 1 < NT) stage(kt + 1);
        __builtin_amdgcn_sched_barrier(0);

        const char* base = lds + (kt & 1) * 32768;
        ulonglong2 afr[4][2], bfr[4][2];
        #pragma unroll
        for (int mf = 0; mf < 4; ++mf) {
            afr[mf][0] = *(const ulonglong2*)(base + (arow + mf * 16) * 128 + ko0);
            afr[mf][1] = *(const ulonglong2*)(base + (arow + mf * 16) * 128 + ko1);
        }
        #pragma unroll
        for (int nf = 0; nf < 4; ++nf) {
            bfr[nf][0] = *(const ulonglong2*)(base + 16384 + (brow + nf * 16) * 128 + ko0);
            bfr[nf][1] = *(const ulonglong2*)(base + 16384 + (brow + nf * 16) * 128 + ko1);
        }
        #pragma unroll
        for (int rd = 0; rd < 2; ++rd)
            #pragma unroll
            for (int hf = 0; hf < 2; ++hf)
                #pragma unroll
                for (int mf = 0; mf < 4; ++mf)
                    #pragma unroll
                    for (int nf = 0; nf < 4; ++nf)
                        acc[mf][nf] = __builtin_amdgcn_mfma_f32_16x16x32_fp8_fp8(
                            (long)(hf ? afr[mf][rd].y : afr[mf][rd].x),
                            (long)(hf ? bfr[nf][rd].y : bfr[nf][rd].x),
                            acc[mf][nf], 0, 0, 0);
    }

    asm volatile("s_waitcnt vmcnt(0)" ::: "memory");
    __builtin_amdgcn_s_barrier();

    // BN + gelu -> bf16 g: [128 col][136 u16] staging
    unsigned short* eL = (unsigned short*)lds;
    #pragma unroll
    for (int mf = 0; mf < 4; ++mf) {
        const int o_l = wm * 64 + mf * 16 + fg * 4;
        f32x4 inv = *(const f32x4*)(bnp + m0 + o_l);
        f32x4 sh  = *(const f32x4*)(bnp + 768 + m0 + o_l);
        #pragma unroll
        for (int nf = 0; nf < 4; ++nf) {
            const int col_l = wn * 64 + nf * 16 + fr;
            u16x4 pk;
            #pragma unroll
            for (int rr = 0; rr < 4; ++rr)
                pk[rr] = f2bf(gelu_fast(acc[mf][nf][rr] * inv[rr] + sh[rr]));
            *(u16x4*)(eL + col_l * 136 + o_l) = pk;
        }
    }
    __builtin_amdgcn_s_barrier();
    #pragma unroll
    for (int i = 0; i < 8; ++i) {
        const int col_l = (t >> 4) + i * 16;
        const int o8 = (t & 15) * 8;
        u16x8 v = *(const u16x8*)(eL + col_l * 136 + o8);
        *(u16x8*)(Out + (size_t)(n0 + col_l) * 768 + m0 + o8) = v;
    }
}

// ---------------- mrconv pass 1 (fp8 y): per-(b, w|h) parity mins ----------------
#define MINSEG (16 * 2 * 56 * 384)
__global__ __launch_bounds__(384)
void mr_min(const unsigned char* __restrict__ y, float* __restrict__ mins)
{
    const int c = threadIdx.x;
    const int q = blockIdx.x;
    const int b = blockIdx.y;
    const unsigned char* yb = y + (size_t)b * P_ * 768;
    float m1e = 3.4e38f, m2e = 3.4e38f, m1o = 3.4e38f, m2o = 3.4e38f;
    if (q < 56) {
        int w = q;
        for (int h = 0; h < 56; h += 2) {
            float v0 = e4m3f(yb[(size_t)(h * 56 + w) * 768 + c]);
            float v1 = e4m3f(yb[(size_t)((h + 1) * 56 + w) * 768 + c]);
            if (v0 < m1e) { m2e = m1e; m1e = v0; } else if (v0 < m2e) m2e = v0;
            if (v1 < m1o) { m2o = m1o; m1o = v1; } else if (v1 < m2o) m2o = v1;
        }
        float* cm1 = mins;
        float* cm2 = mins + MINSEG;
        cm1[((b * 2 + 0) * 56 + w) * 384 + c] = m1e;
        cm1[((b * 2 + 1) * 56 + w) * 384 + c] = m1o;
        cm2[((b * 2 + 0) * 56 + w) * 384 + c] = m2e;
        cm2[((b * 2 + 1) * 56 + w) * 384 + c] = m2o;
    } else {
        int h = q - 56;
        for (int w = 0; w < 56; w += 2) {
            float v0 = e4m3f(yb[(size_t)(h * 56 + w) * 768 + c]);
            float v1 = e4m3f(yb[(size_t)(h * 56 + w + 1) * 768 + c]);
            if (v0 < m1e) { m2e = m1e; m1e = v0; } else if (v0 < m2e) m2e = v0;
            if (v1 < m1o) { m2o = m1o; m1o = v1; } else if (v1 < m2o) m2o = v1;
        }
        float* rm1 = mins + 2 * MINSEG;
        float* rm2 = mins + 3 * MINSEG;
        rm1[((b * 2 + 0) * 56 + h) * 384 + c] = m1e;
        rm1[((b * 2 + 1) * 56 + h) * 384 + c] = m1o;
        rm2[((b * 2 + 0) * 56 + h) * 384 + c] = m2e;
        rm2[((b * 2 + 1) * 56 + h) * 384 + c] = m2o;
    }
}

// ---------------- mrconv pass 2 (fp8 y): combine -> y[:, 384:768] ----------------
__global__ __launch_bounds__(384)
void mr_comb(unsigned char* __restrict__ y, const float* __restrict__ mins)
{
    const int c = threadIdx.x;
    const int h = blockIdx.x;
    const int b = blockIdx.y;
    unsigned char* yb = y + (size_t)b * P_ * 768;
    const float* cm1 = mins;
    const float* cm2 = mins + MINSEG;
    const float* rm1 = mins + 2 * MINSEG;
    const float* rm2 = mins + 3 * MINSEG;
    const int parh = h & 1;
    float r1e = rm1[((b * 2 + 0) * 56 + h) * 384 + c];
    float r2e = rm2[((b * 2 + 0) * 56 + h) * 384 + c];
    float r1o = rm1[((b * 2 + 1) * 56 + h) * 384 + c];
    float r2o = rm2[((b * 2 + 1) * 56 + h) * 384 + c];
    #pragma unroll 2
    for (int w = 0; w < 56; ++w) {
        float v  = e4m3f(yb[(size_t)(h * 56 + w) * 768 + c]);
        float c1 = cm1[((b * 2 + parh) * 56 + w) * 384 + c];
        float c2 = cm2[((b * 2 + parh) * 56 + w) * 384 + c];
        float mh = v > c1 ? c1 : c2;
        float rw1 = (w & 1) ? r1o : r1e;
        float rw2 = (w & 1) ? r2o : r2e;
        float mw = v > rw1 ? rw1 : rw2;
        float xj = fmaxf(0.0f, v - fminf(mh, mw));
        yb[(size_t)(h * 56 + w) * 768 + 384 + c] = (unsigned char)f2e4m3_1(xj);
    }
}

extern "C" void kernel_launch(void* const* d_in, const int* in_sizes, int n_in,
                              void* d_out, int out_size, void* d_ws, size_t ws_size,
                              hipStream_t stream)
{
    const float* x      = (const float*)d_in[0];
    const float* fc1_w  = (const float*)d_in[1];
    const float* fc1_b  = (const float*)d_in[2];
    const float* fc1_g  = (const float*)d_in[3];
    const float* fc1_be = (const float*)d_in[4];
    const float* fc1_m  = (const float*)d_in[5];
    const float* fc1_v  = (const float*)d_in[6];
    const float* gc_w   = (const float*)d_in[7];
    const float* gc_b   = (const float*)d_in[8];
    const float* gc_g   = (const float*)d_in[9];
    const float* gc_be  = (const float*)d_in[10];
    const float* gc_m   = (const float*)d_in[11];
    const float* gc_v   = (const float*)d_in[12];
    const float* fc2_w  = (const float*)d_in[13];
    const float* fc2_b  = (const float*)d_in[14];
    const float* fc2_g  = (const float*)d_in[15];
    const float* fc2_be = (const float*)d_in[16];
    const float* fc2_m  = (const float*)d_in[17];
    const float* fc2_v  = (const float*)d_in[18];

    char* ws = (char*)d_ws;
    unsigned char*  y   = (unsigned char*)ws;                        // [NTOT][768] fp8
    unsigned short* g   = (unsigned short*)(ws + (size_t)NTOT * 768);// [NTOT][768] bf16
    unsigned short* xT  = g + (size_t)NTOT * 768;                    // [NTOT][384] bf16
    unsigned short* wb1 = xT + (size_t)NTOT * 384;                   // [384][384] bf16
    unsigned short* wb3 = wb1 + 384 * 384;                           // [384][768] bf16
    unsigned char*  wb2q = (unsigned char*)(wb3 + 384 * 768);        // [768][768] fp8
    float* bn1 = (float*)(wb2q + 768 * 768);                         // [2][384]
    float* bn2 = bn1 + 2 * 384;                                      // [2][768]
    float* bn3 = bn2 + 2 * 768;                                      // [2][384]
    float* mins = bn3 + 2 * 384;                                     // 4 * MINSEG

    prep_wb<<<1014, 256, 0, stream>>>(fc1_w, gc_w, fc2_w, wb1, wb2q, wb3,
                                      fc1_b, fc1_g, fc1_be, fc1_m, fc1_v,
                                      gc_b, gc_g, gc_be, gc_m, gc_v,
                                      fc2_b, fc2_g, fc2_be, fc2_m, fc2_v,
                                      bn1, bn2, bn3);
    prep_xT<<<dim3(6, 49, 16), 256, 0, stream>>>(x, xT);

    // y[:, 0:384] = bn(fc1 @ x)  (fp8 out)
    gemm1<<<dim3(3 * 392), 256, 0, stream>>>(wb1, xT, y, bn1);
    // y[:, 384:768] = mrconv (two-pass, coalesced, fp8)
    mr_min<<<dim3(112, 16), 384, 0, stream>>>(y, mins);
    mr_comb<<<dim3(56, 16), 384, 0, stream>>>(y, mins);
    // g = gelu(bn(gc @ y))  (fp8 x fp8 -> bf16)
    gemm2q<<<dim3(6 * 392), 256, 0, stream>>>(wb2q, y, g, bn2);
    // out = bn(fc2 @ g) + x
    gemm3<<<dim3(3 * 392), 256, 0, stream>>>(wb3, g, (void*)d_out, bn3, x);
}

// Round 15
// 190.873 us; speedup vs baseline: 1.3500x; 1.1137x over previous
//
#include <hip/hip_runtime.h>

#define P_ 3136
#define NTOT 50176
#define EPSV 1e-5f

typedef __bf16 bf16x8 __attribute__((ext_vector_type(8)));
typedef float f32x4 __attribute__((ext_vector_type(4)));
typedef unsigned short u16x8 __attribute__((ext_vector_type(8)));
typedef unsigned short u16x4 __attribute__((ext_vector_type(4)));

__device__ __forceinline__ unsigned short f2bf(float f) {
    unsigned u = __builtin_bit_cast(unsigned, f);
    unsigned r = u + 0x7fffu + ((u >> 16) & 1u);
    return (unsigned short)(r >> 16);
}
__device__ __forceinline__ float bf2f(unsigned short h) {
    unsigned u = ((unsigned)h) << 16;
    return __builtin_bit_cast(float, u);
}

// ---- OCP e4m3fn encode/decode: hardware cvt when available, SW fallback ----
#if __has_builtin(__builtin_amdgcn_cvt_pk_fp8_f32) && __has_builtin(__builtin_amdgcn_cvt_f32_fp8)
#define FP8_HW 1
#else
#define FP8_HW 0
#endif

__device__ __forceinline__ unsigned f2e4m3_sw(float f) {
    unsigned u = __builtin_bit_cast(unsigned, f);
    unsigned s = (u >> 24) & 0x80u;
    float a = fabsf(f);
    if (a >= 448.f) return s | 0x7Eu;
    if (a < 0.015625f) {
        int m = (int)(a * 512.f + 0.5f);
        return s | (unsigned)m;
    }
    unsigned au = __builtin_bit_cast(unsigned, a);
    unsigned r = au + 0x7FFFFu + ((au >> 20) & 1u);
    unsigned e = (r >> 23) - 120u;
    return s | (e << 3) | ((r >> 20) & 7u);
}
__device__ __forceinline__ float e4m3f_sw(unsigned b) {
    unsigned em = b & 0x7fu;
    float v;
    if (em < 8u) v = (float)em * 0.001953125f;
    else v = __builtin_bit_cast(float, (((em >> 3) + 120u) << 23) | ((em & 7u) << 20));
    return (b & 0x80u) ? -v : v;
}
__device__ __forceinline__ unsigned f2e4m3x4(float v0, float v1, float v2, float v3) {
#if FP8_HW
    unsigned pk = (unsigned)__builtin_amdgcn_cvt_pk_fp8_f32(v0, v1, 0, false);
    pk = (unsigned)__builtin_amdgcn_cvt_pk_fp8_f32(v2, v3, (int)pk, true);
    return pk;
#else
    return f2e4m3_sw(v0) | (f2e4m3_sw(v1) << 8) | (f2e4m3_sw(v2) << 16) | (f2e4m3_sw(v3) << 24);
#endif
}
__device__ __forceinline__ unsigned f2e4m3_1(float v) {
#if FP8_HW
    return (unsigned)__builtin_amdgcn_cvt_pk_fp8_f32(v, 0.f, 0, false) & 0xFFu;
#else
    return f2e4m3_sw(v);
#endif
}
__device__ __forceinline__ float e4m3f(unsigned b) {
#if FP8_HW
    return __builtin_amdgcn_cvt_f32_fp8((int)b, 0);
#else
    return e4m3f_sw(b);
#endif
}

// tanh-approx GELU (max abs err ~1e-3; clamp avoids exp overflow NaN)
__device__ __forceinline__ float gelu_fast(float x) {
    float x2 = x * x;
    float u2 = x * (1.5957691216f + 0.0713548162f * x2);
    u2 = fminf(u2, 80.0f);
    float e = __expf(u2);
    return x * e * __builtin_amdgcn_rcpf(e + 1.0f);
}
__device__ __forceinline__ void gload16(const void* g, void* l) {
    __builtin_amdgcn_global_load_lds(
        (const __attribute__((address_space(1))) void*)g,
        (__attribute__((address_space(3))) void*)l, 16, 0, 0);
}
__device__ __forceinline__ bf16x8 ldlds(const char* p) {
    return __builtin_bit_cast(bf16x8, *(const u16x8*)p);
}

// -------- prep: fc1 -> bf16; gc -> fp8 x32; fc2 -> fp8 x32; BN fold --------
// bn2.inv /= 32 (gc weights x32). bn3.inv /= 256 (fc2 x32, g stored x8).
__global__ __launch_bounds__(256)
void prep_wb(const float* __restrict__ w1, const float* __restrict__ w2,
             const float* __restrict__ w3,
             unsigned short* __restrict__ o1, unsigned char* __restrict__ o2q,
             unsigned char* __restrict__ o3q,
             const float* b1, const float* g1, const float* be1, const float* m1, const float* v1,
             const float* b2, const float* g2, const float* be2, const float* m2, const float* v2,
             const float* b3, const float* g3, const float* be3, const float* m3, const float* v3,
             float* bn1, float* bn2, float* bn3)
{
    int i = blockIdx.x * 256 + threadIdx.x;
    const int n1 = 384 * 384 / 4, n2 = 768 * 768 / 4, n3 = 384 * 768 / 4;
    if (i < n1) {
        float4 f = *(const float4*)(w1 + (size_t)i * 4);
        u16x4 pk = { f2bf(f.x), f2bf(f.y), f2bf(f.z), f2bf(f.w) };
        *(u16x4*)(o1 + (size_t)i * 4) = pk;
    } else if (i < n1 + n2) {
        int j = i - n1;
        float4 f = *(const float4*)(w2 + (size_t)j * 4);
        *(unsigned*)(o2q + (size_t)j * 4) =
            f2e4m3x4(f.x * 32.f, f.y * 32.f, f.z * 32.f, f.w * 32.f);
    } else if (i < n1 + n2 + n3) {
        int j = i - n1 - n2;
        float4 f = *(const float4*)(w3 + (size_t)j * 4);
        *(unsigned*)(o3q + (size_t)j * 4) =
            f2e4m3x4(f.x * 32.f, f.y * 32.f, f.z * 32.f, f.w * 32.f);
    } else {
        int k = i - (n1 + n2 + n3);  // 0..1535
        const float *pb, *pg, *pbe, *pm, *pv; float* dst; int o, M; float isc = 1.f;
        if (k < 384)       { pb=b1; pg=g1; pbe=be1; pm=m1; pv=v1; dst=bn1; o=k;      M=384; }
        else if (k < 1152) { pb=b2; pg=g2; pbe=be2; pm=m2; pv=v2; dst=bn2; o=k-384;  M=768; isc = 1.f/32.f; }
        else               { pb=b3; pg=g3; pbe=be3; pm=m3; pv=v3; dst=bn3; o=k-1152; M=384; isc = 1.f/256.f; }
        float inv = pg[o] / sqrtf(pv[o] + EPSV);
        dst[o]     = inv * isc;
        dst[M + o] = (pb[o] - pm[o]) * inv + pbe[o];
    }
}

// ---------------- prep: x [b][c][p] fp32 -> xT [bp][c] bf16 ----------------
__global__ __launch_bounds__(256)
void prep_xT(const float* __restrict__ x, unsigned short* __restrict__ xT)
{
    __shared__ float tl[64][65];
    const int t = threadIdx.x;
    const int c0 = blockIdx.x * 64;
    const int p0 = blockIdx.y * 64;
    const int b  = blockIdx.z;
    const float* xb = x + ((size_t)b * 384 + c0) * P_ + p0;
    {
        int c = t >> 2, j0 = (t & 3) * 16;
        #pragma unroll
        for (int j = 0; j < 16; j += 4) {
            float4 f4 = *(const float4*)(xb + (size_t)c * P_ + j0 + j);
            tl[c][j0 + j]     = f4.x; tl[c][j0 + j + 1] = f4.y;
            tl[c][j0 + j + 2] = f4.z; tl[c][j0 + j + 3] = f4.w;
        }
    }
    __syncthreads();
    {
        int p = t >> 2, c1 = (t & 3) * 16;
        unsigned short buf[16];
        #pragma unroll
        for (int j = 0; j < 16; ++j) buf[j] = f2bf(tl[c1 + j][p]);
        unsigned short* dst = xT + ((size_t)b * P_ + p0 + p) * 384 + c0 + c1;
        *(u16x8*)dst       = *(u16x8*)buf;
        *(u16x8*)(dst + 8) = *(u16x8*)(buf + 8);
    }
}

// ============ gemm1 (bf16): 128x128x64, 256 thr; BN -> fp8 y [col][768B]+o0 ============
__global__ __launch_bounds__(256, 2)
void gemm1(const unsigned short* __restrict__ W, const unsigned short* __restrict__ In,
           unsigned char* __restrict__ Out, const float* __restrict__ bnp)
{
    constexpr int KD = 384, MDIM = 384, NT = KD / 64, MT = MDIM / 128;
    __shared__ __align__(16) char lds[65536];

    const int t    = threadIdx.x;
    const int lane = t & 63;
    const int wave = t >> 6;
    const int wm = wave >> 1, wn = wave & 1;
    const int fr = lane & 15, fg = lane >> 4;

    const int nwg = gridDim.x;
    int id = blockIdx.x;
    int q = nwg >> 3, r = nwg & 7;
    int xcd = id & 7, pos = id >> 3;
    int wg = (xcd < r ? xcd * (q + 1) : r * (q + 1) + (xcd - r) * q) + pos;
    const int m0 = (wg % MT) * 128;
    const int n0 = (wg / MT) * 128;

    const int pcu  = (((t & 7) ^ ((t >> 3) & 7)) << 3);
    const int srow = t >> 3;
    const unsigned short* pA[4];
    const unsigned short* pB[4];
    #pragma unroll
    for (int i = 0; i < 4; ++i) {
        pA[i] = W  + (size_t)(m0 + i * 32 + srow) * KD + pcu;
        pB[i] = In + (size_t)(n0 + i * 32 + srow) * KD + pcu;
    }
    auto stage = [&](int kt) {
        int kk = kt * 64;
        char* base = lds + (kt & 1) * 32768 + t * 16;
        #pragma unroll
        for (int i = 0; i < 4; ++i) gload16(pA[i] + kk, base + i * 4096);
        #pragma unroll
        for (int i = 0; i < 4; ++i) gload16(pB[i] + kk, base + 16384 + i * 4096);
    };

    const int ko0 = (fg * 16) ^ ((fr & 7) << 4);
    const int ko1 = (64 + fg * 16) ^ ((fr & 7) << 4);
    const int arow = wm * 64 + fr;
    const int brow = wn * 64 + fr;

    f32x4 acc[4][4] = {};

    stage(0);

    for (int kt = 0; kt < NT; ++kt) {
        asm volatile("s_waitcnt vmcnt(0)" ::: "memory");
        __builtin_amdgcn_s_barrier();
        __builtin_amdgcn_sched_barrier(0);
        if (kt + 1 < NT) stage(kt + 1);
        __builtin_amdgcn_sched_barrier(0);

        const char* base = lds + (kt & 1) * 32768;
        bf16x8 afr[4][2], bfr[4][2];
        #pragma unroll
        for (int mf = 0; mf < 4; ++mf) {
            afr[mf][0] = ldlds(base + (arow + mf * 16) * 128 + ko0);
            afr[mf][1] = ldlds(base + (arow + mf * 16) * 128 + ko1);
        }
        #pragma unroll
        for (int nf = 0; nf < 4; ++nf) {
            bfr[nf][0] = ldlds(base + 16384 + (brow + nf * 16) * 128 + ko0);
            bfr[nf][1] = ldlds(base + 16384 + (brow + nf * 16) * 128 + ko1);
        }
        #pragma unroll
        for (int ks = 0; ks < 2; ++ks)
            #pragma unroll
            for (int mf = 0; mf < 4; ++mf)
                #pragma unroll
                for (int nf = 0; nf < 4; ++nf)
                    acc[mf][nf] = __builtin_amdgcn_mfma_f32_16x16x32_bf16(
                        afr[mf][ks], bfr[nf][ks], acc[mf][nf], 0, 0, 0);
    }

    asm volatile("s_waitcnt vmcnt(0)" ::: "memory");
    __builtin_amdgcn_s_barrier();

    // fp8 out: [128 col][144 byte] staging
    unsigned char* eL = (unsigned char*)lds;
    #pragma unroll
    for (int mf = 0; mf < 4; ++mf) {
        const int o_l = wm * 64 + mf * 16 + fg * 4;
        f32x4 inv = *(const f32x4*)(bnp + m0 + o_l);
        f32x4 sh  = *(const f32x4*)(bnp + MDIM + m0 + o_l);
        #pragma unroll
        for (int nf = 0; nf < 4; ++nf) {
            const int col_l = wn * 64 + nf * 16 + fr;
            *(unsigned*)(eL + col_l * 144 + o_l) = f2e4m3x4(
                acc[mf][nf][0] * inv[0] + sh[0],
                acc[mf][nf][1] * inv[1] + sh[1],
                acc[mf][nf][2] * inv[2] + sh[2],
                acc[mf][nf][3] * inv[3] + sh[3]);
        }
    }
    __builtin_amdgcn_s_barrier();
    #pragma unroll
    for (int it = 0; it < 8; ++it) {
        const int idx = it * 256 + t;
        const int col = idx >> 4, seg = idx & 15;
        *(unsigned long long*)(Out + (size_t)(n0 + col) * 768 + m0 + seg * 8) =
            *(const unsigned long long*)(eL + col * 144 + seg * 8);
    }
}

// ============ fp8 GEMM body (gemm2q / gemm3q): 128x128, K-tile=128 fp8, NT=6 ============
// A = Wq fp8 [MDIM][768B], B = In fp8 [NTOT][768B].
// EPI 1: BN+gelu, x8 -> fp8 g [col][768B]+m0.  EPI 2: BN+res -> fp32 [b][o][p].
template<int MDIM, int EPI>
__device__ __forceinline__ void gemmq_body(
    const unsigned char* __restrict__ W,
    const unsigned char* __restrict__ In,
    void* __restrict__ OutV,
    const float* __restrict__ bnp,
    const float* __restrict__ res,
    char* lds)
{
    constexpr int NT = 6;
    constexpr int MT = MDIM / 128;

    const int t    = threadIdx.x;
    const int lane = t & 63;
    const int wave = t >> 6;
    const int wm = wave >> 1, wn = wave & 1;
    const int fr = lane & 15, fg = lane >> 4;

    const int nwg = gridDim.x;
    int id = blockIdx.x;
    int q = nwg >> 3, r = nwg & 7;
    int xcd = id & 7, pos = id >> 3;
    int wg = (xcd < r ? xcd * (q + 1) : r * (q + 1) + (xcd - r) * q) + pos;
    const int m0 = (wg % MT) * 128;
    const int n0 = (wg / MT) * 128;

    const int pcu  = (((t & 7) ^ ((t >> 3) & 7)) << 4);
    const int srow = t >> 3;
    const unsigned char* pA[4];
    const unsigned char* pB[4];
    #pragma unroll
    for (int i = 0; i < 4; ++i) {
        pA[i] = W  + (size_t)(m0 + i * 32 + srow) * 768 + pcu;
        pB[i] = In + (size_t)(n0 + i * 32 + srow) * 768 + pcu;
    }
    auto stage = [&](int kt) {
        int kk = kt * 128;
        char* base = lds + (kt & 1) * 32768 + t * 16;
        #pragma unroll
        for (int i = 0; i < 4; ++i) gload16(pA[i] + kk, base + i * 4096);
        #pragma unroll
        for (int i = 0; i < 4; ++i) gload16(pB[i] + kk, base + 16384 + i * 4096);
    };

    const int ko0 = (fg * 16) ^ ((fr & 7) << 4);
    const int ko1 = (64 + fg * 16) ^ ((fr & 7) << 4);
    const int arow = wm * 64 + fr;
    const int brow = wn * 64 + fr;

    f32x4 acc[4][4] = {};

    stage(0);

    for (int kt = 0; kt < NT; ++kt) {
        asm volatile("s_waitcnt vmcnt(0)" ::: "memory");
        __builtin_amdgcn_s_barrier();
        __builtin_amdgcn_sched_barrier(0);
        if (kt + 1 < NT) stage(kt + 1);
        __builtin_amdgcn_sched_barrier(0);

        const char* base = lds + (kt & 1) * 32768;
        ulonglong2 afr[4][2], bfr[4][2];
        #pragma unroll
        for (int mf = 0; mf < 4; ++mf) {
            afr[mf][0] = *(const ulonglong2*)(base + (arow + mf * 16) * 128 + ko0);
            afr[mf][1] = *(const ulonglong2*)(base + (arow + mf * 16) * 128 + ko1);
        }
        #pragma unroll
        for (int nf = 0; nf < 4; ++nf) {
            bfr[nf][0] = *(const ulonglong2*)(base + 16384 + (brow + nf * 16) * 128 + ko0);
            bfr[nf][1] = *(const ulonglong2*)(base + 16384 + (brow + nf * 16) * 128 + ko1);
        }
        #pragma unroll
        for (int rd = 0; rd < 2; ++rd)
            #pragma unroll
            for (int hf = 0; hf < 2; ++hf)
                #pragma unroll
                for (int mf = 0; mf < 4; ++mf)
                    #pragma unroll
                    for (int nf = 0; nf < 4; ++nf)
                        acc[mf][nf] = __builtin_amdgcn_mfma_f32_16x16x32_fp8_fp8(
                            (long)(hf ? afr[mf][rd].y : afr[mf][rd].x),
                            (long)(hf ? bfr[nf][rd].y : bfr[nf][rd].x),
                            acc[mf][nf], 0, 0, 0);
    }

    asm volatile("s_waitcnt vmcnt(0)" ::: "memory");
    __builtin_amdgcn_s_barrier();

    if (EPI == 1) {
        // BN + gelu -> fp8 g (x8 scale, 1/8 folded into bn3.inv via 1/256 total)
        unsigned char* eL = (unsigned char*)lds;
        unsigned char* Out = (unsigned char*)OutV;
        #pragma unroll
        for (int mf = 0; mf < 4; ++mf) {
            const int o_l = wm * 64 + mf * 16 + fg * 4;
            f32x4 inv = *(const f32x4*)(bnp + m0 + o_l);
            f32x4 sh  = *(const f32x4*)(bnp + MDIM + m0 + o_l);
            #pragma unroll
            for (int nf = 0; nf < 4; ++nf) {
                const int col_l = wn * 64 + nf * 16 + fr;
                *(unsigned*)(eL + col_l * 144 + o_l) = f2e4m3x4(
                    gelu_fast(acc[mf][nf][0] * inv[0] + sh[0]) * 8.f,
                    gelu_fast(acc[mf][nf][1] * inv[1] + sh[1]) * 8.f,
                    gelu_fast(acc[mf][nf][2] * inv[2] + sh[2]) * 8.f,
                    gelu_fast(acc[mf][nf][3] * inv[3] + sh[3]) * 8.f);
            }
        }
        __builtin_amdgcn_s_barrier();
        #pragma unroll
        for (int it = 0; it < 8; ++it) {
            const int idx = it * 256 + t;
            const int col = idx >> 4, seg = idx & 15;
            *(unsigned long long*)(Out + (size_t)(n0 + col) * 768 + m0 + seg * 8) =
                *(const unsigned long long*)(eL + col * 144 + seg * 8);
        }
    } else {
        // BN + residual -> fp32 [b][o][p]
        float* eL = (float*)lds;
        float* Out = (float*)OutV;
        #pragma unroll
        for (int mf = 0; mf < 4; ++mf) {
            const int o_l = wm * 64 + mf * 16 + fg * 4;
            f32x4 inv = *(const f32x4*)(bnp + m0 + o_l);
            f32x4 sh  = *(const f32x4*)(bnp + MDIM + m0 + o_l);
            #pragma unroll
            for (int nf = 0; nf < 4; ++nf) {
                const int col_l = wn * 64 + nf * 16 + fr;
                #pragma unroll
                for (int rr = 0; rr < 4; ++rr)
                    eL[(o_l + rr) * 128 + col_l] = acc[mf][nf][rr] * inv[rr] + sh[rr];
            }
        }
        __builtin_amdgcn_s_barrier();
        const int b0 = n0 / P_;
        const int r0 = n0 - b0 * P_;
        #pragma unroll
        for (int g8 = 0; g8 < 8; ++g8) {
            size_t adr[8]; float ev[8], rv[8];
            #pragma unroll
            for (int u = 0; u < 8; ++u) {
                const int idx = (g8 * 8 + u) * 256 + t;
                const int o_i = idx >> 7, col = idx & 127;
                int p = r0 + col;
                const int wrap = p >= P_;
                p -= wrap ? P_ : 0;
                adr[u] = (size_t)(b0 + wrap) * 384 * P_ + (size_t)(m0 + o_i) * P_ + p;
                ev[u]  = eL[o_i * 128 + col];
                rv[u]  = res[adr[u]];
            }
            #pragma unroll
            for (int u = 0; u < 8; ++u)
                Out[adr[u]] = ev[u] + rv[u];
        }
    }
}

__global__ __launch_bounds__(256, 2)
void gemm2q(const unsigned char* __restrict__ W, const unsigned char* __restrict__ In,
            void* __restrict__ OutV, const float* __restrict__ bnp)
{
    __shared__ __align__(16) char lds[65536];
    gemmq_body<768, 1>(W, In, OutV, bnp, nullptr, lds);
}
__global__ __launch_bounds__(256, 2)
void gemm3q(const unsigned char* __restrict__ W, const unsigned char* __restrict__ In,
            void* __restrict__ OutV, const float* __restrict__ bnp,
            const float* __restrict__ res)
{
    __shared__ __align__(16) char lds[65536];
    gemmq_body<384, 2>(W, In, OutV, bnp, res, lds);
}

// ---------------- mrconv pass 1 (fp8 y): per-(b, w|h) parity mins ----------------
#define MINSEG (16 * 2 * 56 * 384)
__global__ __launch_bounds__(384)
void mr_min(const unsigned char* __restrict__ y, float* __restrict__ mins)
{
    const int c = threadIdx.x;
    const int q = blockIdx.x;
    const int b = blockIdx.y;
    const unsigned char* yb = y + (size_t)b * P_ * 768;
    float m1e = 3.4e38f, m2e = 3.4e38f, m1o = 3.4e38f, m2o = 3.4e38f;
    if (q < 56) {
        int w = q;
        for (int h = 0; h < 56; h += 2) {
            float v0 = e4m3f(yb[(size_t)(h * 56 + w) * 768 + c]);
            float v1 = e4m3f(yb[(size_t)((h + 1) * 56 + w) * 768 + c]);
            if (v0 < m1e) { m2e = m1e; m1e = v0; } else if (v0 < m2e) m2e = v0;
            if (v1 < m1o) { m2o = m1o; m1o = v1; } else if (v1 < m2o) m2o = v1;
        }
        float* cm1 = mins;
        float* cm2 = mins + MINSEG;
        cm1[((b * 2 + 0) * 56 + w) * 384 + c] = m1e;
        cm1[((b * 2 + 1) * 56 + w) * 384 + c] = m1o;
        cm2[((b * 2 + 0) * 56 + w) * 384 + c] = m2e;
        cm2[((b * 2 + 1) * 56 + w) * 384 + c] = m2o;
    } else {
        int h = q - 56;
        for (int w = 0; w < 56; w += 2) {
            float v0 = e4m3f(yb[(size_t)(h * 56 + w) * 768 + c]);
            float v1 = e4m3f(yb[(size_t)(h * 56 + w + 1) * 768 + c]);
            if (v0 < m1e) { m2e = m1e; m1e = v0; } else if (v0 < m2e) m2e = v0;
            if (v1 < m1o) { m2o = m1o; m1o = v1; } else if (v1 < m2o) m2o = v1;
        }
        float* rm1 = mins + 2 * MINSEG;
        float* rm2 = mins + 3 * MINSEG;
        rm1[((b * 2 + 0) * 56 + h) * 384 + c] = m1e;
        rm1[((b * 2 + 1) * 56 + h) * 384 + c] = m1o;
        rm2[((b * 2 + 0) * 56 + h) * 384 + c] = m2e;
        rm2[((b * 2 + 1) * 56 + h) * 384 + c] = m2o;
    }
}

// ---------------- mrconv pass 2 (fp8 y): combine -> y[:, 384:768] ----------------
__global__ __launch_bounds__(384)
void mr_comb(unsigned char* __restrict__ y, const float* __restrict__ mins)
{
    const int c = threadIdx.x;
    const int h = blockIdx.x;
    const int b = blockIdx.y;
    unsigned char* yb = y + (size_t)b * P_ * 768;
    const float* cm1 = mins;
    const float* cm2 = mins + MINSEG;
    const float* rm1 = mins + 2 * MINSEG;
    const float* rm2 = mins + 3 * MINSEG;
    const int parh = h & 1;
    float r1e = rm1[((b * 2 + 0) * 56 + h) * 384 + c];
    float r2e = rm2[((b * 2 + 0) * 56 + h) * 384 + c];
    float r1o = rm1[((b * 2 + 1) * 56 + h) * 384 + c];
    float r2o = rm2[((b * 2 + 1) * 56 + h) * 384 + c];
    #pragma unroll 2
    for (int w = 0; w < 56; ++w) {
        float v  = e4m3f(yb[(size_t)(h * 56 + w) * 768 + c]);
        float c1 = cm1[((b * 2 + parh) * 56 + w) * 384 + c];
        float c2 = cm2[((b * 2 + parh) * 56 + w) * 384 + c];
        float mh = v > c1 ? c1 : c2;
        float rw1 = (w & 1) ? r1o : r1e;
        float rw2 = (w & 1) ? r2o : r2e;
        float mw = v > rw1 ? rw1 : rw2;
        float xj = fmaxf(0.0f, v - fminf(mh, mw));
        yb[(size_t)(h * 56 + w) * 768 + 384 + c] = (unsigned char)f2e4m3_1(xj);
    }
}

extern "C" void kernel_launch(void* const* d_in, const int* in_sizes, int n_in,
                              void* d_out, int out_size, void* d_ws, size_t ws_size,
                              hipStream_t stream)
{
    const float* x      = (const float*)d_in[0];
    const float* fc1_w  = (const float*)d_in[1];
    const float* fc1_b  = (const float*)d_in[2];
    const float* fc1_g  = (const float*)d_in[3];
    const float* fc1_be = (const float*)d_in[4];
    const float* fc1_m  = (const float*)d_in[5];
    const float* fc1_v  = (const float*)d_in[6];
    const float* gc_w   = (const float*)d_in[7];
    const float* gc_b   = (const float*)d_in[8];
    const float* gc_g   = (const float*)d_in[9];
    const float* gc_be  = (const float*)d_in[10];
    const float* gc_m   = (const float*)d_in[11];
    const float* gc_v   = (const float*)d_in[12];
    const float* fc2_w  = (const float*)d_in[13];
    const float* fc2_b  = (const float*)d_in[14];
    const float* fc2_g  = (const float*)d_in[15];
    const float* fc2_be = (const float*)d_in[16];
    const float* fc2_m  = (const float*)d_in[17];
    const float* fc2_v  = (const float*)d_in[18];

    char* ws = (char*)d_ws;
    unsigned char*  y   = (unsigned char*)ws;                        // [NTOT][768] fp8
    unsigned char*  g   = y + (size_t)NTOT * 768;                    // [NTOT][768] fp8 (x8)
    unsigned short* xT  = (unsigned short*)(g + (size_t)NTOT * 768); // [NTOT][384] bf16
    unsigned short* wb1 = xT + (size_t)NTOT * 384;                   // [384][384] bf16
    unsigned char*  wb2q = (unsigned char*)(wb1 + 384 * 384);        // [768][768] fp8 x32
    unsigned char*  wb3q = wb2q + 768 * 768;                         // [384][768] fp8 x32
    float* bn1 = (float*)(wb3q + 384 * 768);                         // [2][384]
    float* bn2 = bn1 + 2 * 384;                                      // [2][768]
    float* bn3 = bn2 + 2 * 768;                                      // [2][384]
    float* mins = bn3 + 2 * 384;                                     // 4 * MINSEG

    prep_wb<<<1014, 256, 0, stream>>>(fc1_w, gc_w, fc2_w, wb1, wb2q, wb3q,
                                      fc1_b, fc1_g, fc1_be, fc1_m, fc1_v,
                                      gc_b, gc_g, gc_be, gc_m, gc_v,
                                      fc2_b, fc2_g, fc2_be, fc2_m, fc2_v,
                                      bn1, bn2, bn3);
    prep_xT<<<dim3(6, 49, 16), 256, 0, stream>>>(x, xT);

    // y[:, 0:384] = bn(fc1 @ x)  (fp8 out)
    gemm1<<<dim3(3 * 392), 256, 0, stream>>>(wb1, xT, y, bn1);
    // y[:, 384:768] = mrconv (two-pass, coalesced, fp8)
    mr_min<<<dim3(112, 16), 384, 0, stream>>>(y, mins);
    mr_comb<<<dim3(56, 16), 384, 0, stream>>>(y, mins);
    // g = gelu(bn(gc @ y)) * 8  (fp8 x fp8 -> fp8)
    gemm2q<<<dim3(6 * 392), 256, 0, stream>>>(wb2q, y, g, bn2);
    // out = bn(fc2 @ g)/256-fold + x  (fp8 x fp8 -> fp32 + residual)
    gemm3q<<<dim3(3 * 392), 256, 0, stream>>>(wb3q, g, (void*)d_out, bn3, x);
}